// Round 6
// baseline (1373.618 us; speedup 1.0000x reference)
//
#include <hip/hip_runtime.h>
#include <hip/hip_bf16.h>

#define BATCH 131072
#define H 256
#define NBLK 8
#define NMID 3
#define MS 16            // samples per workgroup
#define RT_N 3           // 3 streams x 1 row-tile (16 samples)
#define NT 256           // 4 waves; each wave owns 4 column-tiles
#define CT_N 4

typedef __attribute__((ext_vector_type(8))) short short8;   // 8 bf16 = 4 VGPRs (MFMA A/B frag)
typedef __attribute__((ext_vector_type(4))) float f32x4;    // MFMA C/D frag

// Workgroup barrier WITHOUT the vmcnt(0) drain __syncthreads forces:
// LDS ordering needs only lgkmcnt(0); in-flight global loads survive.
__device__ __forceinline__ void barrier_lgkm() {
    asm volatile("s_waitcnt lgkmcnt(0)\n\ts_barrier" ::: "memory");
}

// pack two f32 -> packed bf16 pair (round-half-up): 2 adds + v_perm.
__device__ __forceinline__ unsigned pk2(float a, float b) {
    unsigned ua = __float_as_uint(a) + 0x8000u;
    unsigned ub = __float_as_uint(b) + 0x8000u;
    return __builtin_amdgcn_perm(ub, ua, 0x07060302u);
}

// Pack Wm into MFMA B-frag order bf16, column-permuted so each epilogue thread
// owns cols {c,c+1} and {c+32,c+33}, c = wave*64 + mcol*2:
//   tile T = wave*4+ct covers n = (T>>2)*64 + (T&1)*32 + m*2 + ((T>>1)&1).
__global__ void pack_w_kernel(const float* __restrict__ Wm, unsigned short* __restrict__ Wp) {
    int o = blockIdx.x * blockDim.x + threadIdx.x;   // 24 * 8192 chunks
    if (o >= NBLK * NMID * 8192) return;
    int lane  = o & 63;
    int T     = (o >> 6) & 15;
    int kk    = (o >> 10) & 7;
    int layer = o >> 13;
    int n  = (T >> 2) * 64 + (T & 1) * 32 + (lane & 15) * 2 + ((T >> 1) & 1);
    int k0 = kk * 32 + (lane >> 4) * 8;
    const float* src = Wm + (size_t)layer * H * H;
    unsigned int w[4];
    #pragma unroll
    for (int jj = 0; jj < 4; ++jj)
        w[jj] = pk2(src[(size_t)(k0 + 2*jj) * H + n], src[(size_t)(k0 + 2*jj + 1) * H + n]);
    uint4 val; val.x = w[0]; val.y = w[1]; val.z = w[2]; val.w = w[3];
    ((uint4*)Wp)[o] = val;
}

struct Packs { unsigned ph[4][2]; unsigned pa[4][2]; unsigned pb[4][2]; };  // [r][colgrp]

__device__ __forceinline__ void epi_compute(const f32x4 (&acc)[RT_N][CT_N],
                                            const float2 bvA, const float2 bvB, Packs& p) {
    #pragma unroll
    for (int r = 0; r < 4; ++r) {
        float a0 = acc[0][0][r] + bvA.x, a1 = acc[0][2][r] + bvA.y;
        float b0 = acc[0][1][r] + bvB.x, b1 = acc[0][3][r] + bvB.y;
        bool ma0 = a0 > 0.f, ma1 = a1 > 0.f, mb0 = b0 > 0.f, mb1 = b1 > 0.f;
        p.ph[r][0] = pk2(ma0 ? a0 : 0.f,            ma1 ? a1 : 0.f);
        p.ph[r][1] = pk2(mb0 ? b0 : 0.f,            mb1 ? b1 : 0.f);
        p.pa[r][0] = pk2(ma0 ? acc[1][0][r] : 0.f,  ma1 ? acc[1][2][r] : 0.f);
        p.pa[r][1] = pk2(mb0 ? acc[1][1][r] : 0.f,  mb1 ? acc[1][3][r] : 0.f);
        p.pb[r][0] = pk2(ma0 ? acc[2][0][r] : 0.f,  ma1 ? acc[2][2][r] : 0.f);
        p.pb[r][1] = pk2(mb0 ? acc[2][1][r] : 0.f,  mb1 ? acc[2][3][r] : 0.f);
    }
}

// write next layer's A-frag X. X layout: [3 st][8 kk][64 slots][8 bf16].
__device__ __forceinline__ void epi_store(const Packs& p, unsigned short* __restrict__ Xs,
                                          int wave, int lane) {
    const int mcol = lane & 15, quad = lane >> 4;
    const int qx = mcol >> 2;
    const int jb = (mcol & 3) * 2;
    const int kkA = wave * 2;
    #pragma unroll
    for (int r = 0; r < 4; ++r) {
        int le  = qx * 16 + quad * 4 + r;
        int scl = le ^ ((le >> 3) & 7);
        int e0  = kkA * 512 + scl * 8 + jb;
        *(unsigned*)(Xs + e0)               = p.ph[r][0];
        *(unsigned*)(Xs + e0 + 512)         = p.ph[r][1];
        *(unsigned*)(Xs + e0 + 4096)        = p.pa[r][0];
        *(unsigned*)(Xs + e0 + 4096 + 512)  = p.pa[r][1];
        *(unsigned*)(Xs + e0 + 8192)        = p.pb[r][0];
        *(unsigned*)(Xs + e0 + 8192 + 512)  = p.pb[r][1];
    }
}

__global__ __launch_bounds__(NT, 2)
void flow_kernel(const float* __restrict__ x, const float* __restrict__ v,
                 const float* __restrict__ Wi, const float* __restrict__ bi,
                 const float* __restrict__ bm, const float* __restrict__ Wo,
                 const float* __restrict__ bo,
                 const unsigned short* __restrict__ Wp,
                 float* __restrict__ out)
{
    __shared__ uint4 Xbuf[2][RT_N * 8 * 64];   // 2 x 24 KiB, double-buffered X
    __shared__ float zbuf[MS * 2];
    __shared__ float vbuf[MS * 2];

    const int tid  = threadIdx.x;
    const int wave = tid >> 6;
    const int lane = tid & 63;
    const int mcol = lane & 15;
    const int quad = lane >> 4;
    const int s0   = blockIdx.x * MS;
    const int rl   = lane ^ ((lane >> 3) & 7);   // swizzled A-read slot

    float dlp = 0.0f;
    if (tid < MS) {
        zbuf[tid*2+0] = x[(size_t)(s0+tid)*2+0];
        zbuf[tid*2+1] = x[(size_t)(s0+tid)*2+1];
        vbuf[tid*2+0] = v[(size_t)(s0+tid)*2+0];
        vbuf[tid*2+1] = v[(size_t)(s0+tid)*2+1];
    }
    __syncthreads();

    const int cA = wave * 64 + mcol * 2;

    for (int b = 0; b < NBLK; ++b) {
        const short8* Bp_base = ((const short8*)Wp) + (size_t)(b * NMID) * 8192;
        short8 bf[2][CT_N];                      // B-register pipeline (depth 2)

        // ------- layer 0: 2 -> 256 via MFMA; frags in registers -------
        {
            // pre-issue mid-layer-0's kk=0,1 B tiles (in flight across barriers)
            #pragma unroll
            for (int ct = 0; ct < CT_N; ++ct)
                bf[0][ct] = Bp_base[(0*16 + wave*4 + ct)*64 + lane];
            #pragma unroll
            for (int ct = 0; ct < CT_N; ++ct)
                bf[1][ct] = Bp_base[(1*16 + wave*4 + ct)*64 + lane];

            const float* Wi0 = Wi + (size_t)b * 2 * H;
            const float* Wi1 = Wi0 + H;
            short8 b0[CT_N];
            #pragma unroll
            for (int ct = 0; ct < CT_N; ++ct) {
                short8 z = {0,0,0,0,0,0,0,0};
                if (quad == 0) {
                    int n = cA + (ct & 1) * 32 + (ct >> 1);
                    unsigned p = pk2(Wi0[n], Wi1[n]);
                    z[0] = (short)(p & 0xFFFFu);
                    z[1] = (short)(p >> 16);
                }
                b0[ct] = z;
            }
            f32x4 acc[RT_N][CT_N];
            #pragma unroll
            for (int st = 0; st < RT_N; ++st)
                #pragma unroll
                for (int ct = 0; ct < CT_N; ++ct)
                    acc[st][ct] = (f32x4){0.f, 0.f, 0.f, 0.f};
            #pragma unroll
            for (int st = 0; st < RT_N; ++st) {
                short8 af = {0,0,0,0,0,0,0,0};
                if (quad == 0) {
                    if (st == 0) {
                        unsigned p = pk2(zbuf[mcol*2+0], zbuf[mcol*2+1]);
                        af[0] = (short)(p & 0xFFFFu);
                        af[1] = (short)(p >> 16);
                    } else if (st == 1) af[0] = (short)0x3F80;
                    else                af[1] = (short)0x3F80;
                }
                #pragma unroll
                for (int ct = 0; ct < CT_N; ++ct)
                    acc[st][ct] = __builtin_amdgcn_mfma_f32_16x16x32_bf16(af, b0[ct], acc[st][ct], 0, 0, 0);
            }
            Packs p;
            const float* bib = bi + (size_t)b * H;
            epi_compute(acc, *(const float2*)(bib + cA), *(const float2*)(bib + cA + 32), p);
            epi_store(p, (unsigned short*)Xbuf[0], wave, lane);
            barrier_lgkm();
        }

        // ------- mid layers: read buf rb, write buf wb; 1 barrier each -------
        #pragma unroll
        for (int li = 0; li < NMID; ++li) {
            const int rb = li & 1, wb = rb ^ 1;
            const short8* Bp = Bp_base + (size_t)li * 8192;
            const short8* Bn = Bp + 8192;        // next layer (only li<2)

            f32x4 acc[RT_N][CT_N];
            #pragma unroll
            for (int st = 0; st < RT_N; ++st)
                #pragma unroll
                for (int ct = 0; ct < CT_N; ++ct)
                    acc[st][ct] = (f32x4){0.f, 0.f, 0.f, 0.f};

            #pragma unroll
            for (int kk = 0; kk < 8; ++kk) {
                #pragma unroll
                for (int st = 0; st < RT_N; ++st) {
                    short8 af = ((const short8*)Xbuf[rb])[(st*8 + kk)*64 + rl];
                    #pragma unroll
                    for (int ct = 0; ct < CT_N; ++ct)
                        acc[st][ct] = __builtin_amdgcn_mfma_f32_16x16x32_bf16(af, bf[kk & 1][ct], acc[st][ct], 0, 0, 0);
                }
                // refill this kk's buffer for kk+2 (or next layer's kk0/kk1)
                if (kk < 6) {
                    #pragma unroll
                    for (int ct = 0; ct < CT_N; ++ct)
                        bf[kk & 1][ct] = Bp[((kk+2)*16 + wave*4 + ct)*64 + lane];
                } else if (li < NMID - 1) {
                    #pragma unroll
                    for (int ct = 0; ct < CT_N; ++ct)
                        bf[kk & 1][ct] = Bn[((kk-6)*16 + wave*4 + ct)*64 + lane];
                }
            }
            Packs p;
            const float* bmb = bm + (size_t)(b * NMID + li) * H;
            epi_compute(acc, *(const float2*)(bmb + cA), *(const float2*)(bmb + cA + 32), p);
            epi_store(p, (unsigned short*)Xbuf[wb], wave, lane);
            barrier_lgkm();
        }

        // ------- layer 4: 256 -> 2 via MFMA; reads Xbuf[1], partials in Xbuf[0] -------
        {
            const float* Wob = Wo + (size_t)b * H * 2;
            const float* bob = bo + (size_t)b * 2;
            short8 b4[2];
            #pragma unroll
            for (int kki = 0; kki < 2; ++kki) {
                short8 z = {0,0,0,0,0,0,0,0};
                if (mcol < 2) {
                    int kb = (wave * 2 + kki) * 32 + quad * 8;
                    #pragma unroll
                    for (int jj = 0; jj < 4; ++jj) {
                        unsigned p = pk2(Wob[(kb + 2*jj) * 2 + mcol], Wob[(kb + 2*jj + 1) * 2 + mcol]);
                        z[2*jj]   = (short)(p & 0xFFFFu);
                        z[2*jj+1] = (short)(p >> 16);
                    }
                }
                b4[kki] = z;
            }
            f32x4 accL[RT_N];
            #pragma unroll
            for (int st = 0; st < RT_N; ++st) accL[st] = (f32x4){0.f, 0.f, 0.f, 0.f};
            #pragma unroll
            for (int st = 0; st < RT_N; ++st) {
                #pragma unroll
                for (int kki = 0; kki < 2; ++kki) {
                    short8 af = ((const short8*)Xbuf[1])[(st*8 + wave*2 + kki)*64 + rl];
                    accL[st] = __builtin_amdgcn_mfma_f32_16x16x32_bf16(af, b4[kki], accL[st], 0, 0, 0);
                }
            }
            // scatter partials into Xbuf[0] region (no readers of buf0 remain)
            float* part = (float*)Xbuf[0];       // [48 rows][2 cols][4 waves] = 384 floats
            if (mcol < 2) {
                #pragma unroll
                for (int st = 0; st < RT_N; ++st)
                    #pragma unroll
                    for (int r = 0; r < 4; ++r)
                        part[((st*16 + quad*4 + r)*2 + mcol)*4 + wave] = accL[st][r];
            }
            barrier_lgkm();
            float* res = part + 384;             // 96 floats
            if (tid < 96) {
                float4 p4 = ((const float4*)part)[tid];
                res[tid] = p4.x + p4.y + p4.z + p4.w;
            }
            barrier_lgkm();
            if (tid < MS) {
                float SH0 = res[tid*2],      SH1 = res[tid*2+1];
                float SA0 = res[32 + tid*2], SA1 = res[33 + tid*2];
                float SB0 = res[64 + tid*2], SB1 = res[65 + tid*2];
                float pre0 = SH0 + bob[0], pre1 = SH1 + bob[1];
                bool  m0 = pre0 > 0.f,     m1 = pre1 > 0.f;
                float gx0 = m0 ? pre0 : 0.f, gx1 = m1 ? pre1 : 0.f;
                float J00 = m0 ? SA0 : 0.f;
                float J01 = m0 ? SB0 : 0.f;
                float J10 = m1 ? SA1 : 0.f;
                float J11 = m1 ? SB1 : 0.f;
                float v0 = vbuf[tid*2+0], v1 = vbuf[tid*2+1];
                float w0 = v0, w1 = v1, ld = 0.f;
                const float coef[5] = {1.f, -0.5f, 1.f/3.f, -0.25f, 0.2f};
                #pragma unroll
                for (int k = 0; k < 5; ++k) {
                    float nw0 = fmaf(J00, w0, J01 * w1);
                    float nw1 = fmaf(J10, w0, J11 * w1);
                    w0 = nw0; w1 = nw1;
                    ld = fmaf(coef[k], fmaf(w0, v0, w1 * v1), ld);
                }
                zbuf[tid*2+0] += gx0;
                zbuf[tid*2+1] += gx1;
                dlp -= ld;
            }
            barrier_lgkm();
        }
    }

    if (tid < MS) {
        out[(size_t)(s0+tid)*2+0] = zbuf[tid*2+0];
        out[(size_t)(s0+tid)*2+1] = zbuf[tid*2+1];
        out[(size_t)2*BATCH + s0 + tid] = dlp;
    }
}

extern "C" void kernel_launch(void* const* d_in, const int* in_sizes, int n_in,
                              void* d_out, int out_size, void* d_ws, size_t ws_size,
                              hipStream_t stream) {
    const float* x  = (const float*)d_in[0];
    const float* v  = (const float*)d_in[1];
    const float* Wi = (const float*)d_in[2];
    const float* bi = (const float*)d_in[3];
    const float* Wm = (const float*)d_in[4];
    const float* bm = (const float*)d_in[5];
    const float* Wo = (const float*)d_in[6];
    const float* bo = (const float*)d_in[7];
    unsigned short* Wp = (unsigned short*)d_ws;   // 24*65536*2 = 3 MiB

    int nchunks = NBLK * NMID * 8192;
    pack_w_kernel<<<(nchunks + 255) / 256, 256, 0, stream>>>(Wm, Wp);
    flow_kernel<<<BATCH / MS, NT, 0, stream>>>(x, v, Wi, bi, bm, Wo, bo, Wp, (float*)d_out);
}